// Round 4
// baseline (221.439 us; speedup 1.0000x reference)
//
#include <hip/hip_runtime.h>
#include <math.h>

#define Wd 512
#define Hd 512
#define Bd 32
#define PLANE (Hd * Wd)

// k_rotate staging window (SoA, 4 planes: r,g,b,mask). Worst-case needed:
// 32x16 tile, any angle: floor-span <= 35 -> +2 corners +2 guard = 39 rows;
// cols 39 + <=3 align slack = 42 -> OPW 44 (multiple of 4 for float4 chunks).
#define OPW 44
#define OPH 39
#define OPP (OPH * OPW)          // 1716 floats per plane
#define NCHUNK (4 * OPH * (OPW / 4))   // 1716 float4 chunks (fast path)

// k_affine staging window (AoS float4 cells); scale>=0.9 -> cols<=39, rows<=21
#define RPW 40
#define RPH 22

__device__ __forceinline__ float clip01(float x) { return fminf(fmaxf(x, 0.f), 1.f); }

// ---------------------------------------------------------------------------
// K1: flip + rotate -> AoS float4 intermediate in ws.
// 32x16 tile per block (256 thr, 2px/thread). SoA LDS staging with interior
// fast path (aligned float4 chunk loads, flips folded) and predicated
// zero-filling slow path for boundary blocks.
// ---------------------------------------------------------------------------
__global__ __launch_bounds__(256) void k_rotate(const float* __restrict__ imgs,
                                                const float* __restrict__ masks,
                                                const int* __restrict__ hflip,
                                                const int* __restrict__ vflip,
                                                const float* __restrict__ angles,
                                                float4* __restrict__ rot)
{
    __shared__ float sP[4 * OPP];      // 27456 B

    const int tx = threadIdx.x, ty = threadIdx.y;
    const int tid = ty * 32 + tx;
    const int bx = blockIdx.x * 32, by = blockIdx.y * 16;
    const int b = blockIdx.z;

    const float cx = (Wd - 1) * 0.5f, cy = (Hd - 1) * 0.5f;
    const float th = angles[b] * 0.017453292519943295f;
    const float c = cosf(th), s = sinf(th);
    const bool hf = hflip[b] > 0, vf = vflip[b] > 0;

    // bbox from the 4 tile corners; expression identical to per-pixel below
    float minsx, maxsx, minsy, maxsy;
    {
        const float xs0 = (float)bx - cx, xs1 = (float)(bx + 31) - cx;
        const float ys0 = (float)by - cy, ys1 = (float)(by + 15) - cy;
        float a0 = c * xs0 + s * ys0 + cx, a1 = c * xs1 + s * ys0 + cx;
        float a2 = c * xs0 + s * ys1 + cx, a3 = c * xs1 + s * ys1 + cx;
        minsx = fminf(fminf(a0, a1), fminf(a2, a3));
        maxsx = fmaxf(fmaxf(a0, a1), fmaxf(a2, a3));
        float b0 = -s * xs0 + c * ys0 + cy, b1 = -s * xs1 + c * ys0 + cy;
        float b2 = -s * xs0 + c * ys1 + cy, b3 = -s * xs1 + c * ys1 + cy;
        minsy = fminf(fminf(b0, b1), fminf(b2, b3));
        maxsy = fmaxf(fmaxf(b0, b1), fmaxf(b2, b3));
        (void)maxsx; (void)maxsy;
    }
    const int ox0 = (int)floorf(minsx) - 1;
    const int oy0 = (int)floorf(minsy) - 1;
    const int oxa = ox0 & ~3;          // align down for float4 chunks

    const float* pl0 = imgs + (size_t)b * 3 * PLANE;
    const float* mb  = masks + (size_t)b * PLANE;

    const bool fastp = (oxa >= 0) && (oy0 >= 0) &&
                       (oxa + OPW <= Wd) && (oy0 + OPH <= Hd);

    if (fastp) {
        // stage full OPH x OPW window: 4 planes x 39 rows x 11 float4 chunks
        for (int idx = tid; idx < NCHUNK; idx += 256) {
            int p   = idx / (OPH * (OPW / 4));           // /429
            int rem = idx - p * (OPH * (OPW / 4));
            int row = rem / (OPW / 4);                   // /11
            int c4  = rem - row * (OPW / 4);
            const float* src = (p == 3) ? mb : pl0 + p * PLANE;
            int gy = oy0 + row;
            int fy = vf ? (Hd - 1 - gy) : gy;
            float4 v;
            if (!hf) {
                v = *(const float4*)(src + fy * Wd + (oxa + 4 * c4));
            } else {
                // cells col=4c4..4c4+3 <- img[fy][511-(oxa+col)], reversed chunk
                float4 t = *(const float4*)(src + fy * Wd + (Wd - 4 - oxa - 4 * c4));
                v = make_float4(t.w, t.z, t.y, t.x);
            }
            *(float4*)&sP[p * OPP + row * OPW + 4 * c4] = v;
        }
    } else {
        for (int idx = tid; idx < 4 * OPP; idx += 256) {
            int p   = idx / OPP;
            int rem = idx - p * OPP;
            int row = rem / OPW;
            int col = rem - row * OPW;
            int gy = oy0 + row, gx = oxa + col;
            float v = 0.f;
            if ((unsigned)gy < (unsigned)Hd && (unsigned)gx < (unsigned)Wd) {
                int fy = vf ? (Hd - 1 - gy) : gy;
                int fx = hf ? (Wd - 1 - gx) : gx;
                const float* src = (p == 3) ? mb : pl0 + p * PLANE;
                v = src[fy * Wd + fx];
            }
            sP[idx] = v;
        }
    }
    __syncthreads();

    #pragma unroll
    for (int k = 0; k < 2; ++k) {
        int x = bx + tx, y = by + ty + k * 8;
        float dx = (float)x - cx, dy = (float)y - cy;
        float sx = c * dx + s * dy + cx;
        float sy = -s * dx + c * dy + cy;
        float sxl = sx - (float)oxa;
        float syl = sy - (float)oy0;
        float x0f = floorf(sxl), y0f = floorf(syl);
        float wx = sxl - x0f, wy = syl - y0f;
        int xi = min(max((int)x0f, 0), OPW - 2);
        int yi = min(max((int)y0f, 0), OPH - 2);
        float w00 = (1.f - wx) * (1.f - wy);
        float w10 = wx * (1.f - wy);
        float w01 = (1.f - wx) * wy;
        float w11 = wx * wy;
        int base = yi * OPW + xi;
        float4 o;
        float* op = (float*)&o;
        #pragma unroll
        for (int p = 0; p < 4; ++p) {
            const float* sp = sP + p * OPP + base;
            op[p] = w00 * sp[0] + w10 * sp[1] + w01 * sp[OPW] + w11 * sp[OPW + 1];
        }
        rot[(size_t)b * PLANE + (size_t)y * Wd + x] = o;
    }
}

// ---------------------------------------------------------------------------
// K2: affine from AoS intermediate + brightness -> planar d_out + gray partials.
// 32x16 tile, block (16,16), 2px/thread along x (float2 stores).
// ---------------------------------------------------------------------------
__global__ __launch_bounds__(256) void k_affine(const float4* __restrict__ rot,
                                                const float* __restrict__ translate,
                                                const float* __restrict__ scale,
                                                const float* __restrict__ brightness,
                                                float* __restrict__ oimgs,
                                                float* __restrict__ omasks,
                                                float* __restrict__ partials)
{
    __shared__ float4 tile[RPH * RPW];     // 14080 B

    const int tx2 = threadIdx.x;           // 0..15
    const int ty  = threadIdx.y;           // 0..15
    const int tid = ty * 16 + tx2;
    const int bx = blockIdx.x * 32, by = blockIdx.y * 16;
    const int b = blockIdx.z;

    const float cx = (Wd - 1) * 0.5f, cy = (Hd - 1) * 0.5f;
    const float txf = translate[2 * b] * (float)Wd;
    const float tyf = translate[2 * b + 1] * (float)Hd;
    const float sc = scale[b];
    const float bf = brightness[b];

    // corners, identical expression to per-pixel
    float ax0 = ((float)bx - cx - txf) / sc + cx;
    float ax1 = ((float)(bx + 31) - cx - txf) / sc + cx;
    float ay0 = ((float)by - cy - tyf) / sc + cy;
    float ay1 = ((float)(by + 15) - cy - tyf) / sc + cy;
    const int rx0 = (int)floorf(fminf(ax0, ax1)) - 1;
    const int ry0 = (int)floorf(fminf(ay0, ay1)) - 1;

    const float4* src = rot + (size_t)b * PLANE;
    const bool fastp = (rx0 >= 0) && (ry0 >= 0) &&
                       (rx0 + RPW <= Wd) && (ry0 + RPH <= Hd);

    if (fastp) {
        for (int idx = tid; idx < RPH * RPW; idx += 256) {
            int row = idx / RPW;
            int col = idx - row * RPW;
            tile[idx] = src[(ry0 + row) * Wd + rx0 + col];
        }
    } else {
        for (int idx = tid; idx < RPH * RPW; idx += 256) {
            int row = idx / RPW;
            int col = idx - row * RPW;
            int gy = ry0 + row, gx = rx0 + col;
            float4 v = make_float4(0.f, 0.f, 0.f, 0.f);
            if ((unsigned)gy < (unsigned)Hd && (unsigned)gx < (unsigned)Wd)
                v = src[gy * Wd + gx];
            tile[idx] = v;
        }
    }
    __syncthreads();

    float grays = 0.f;
    float rr[2], gg[2], bb[2], mm[2];
    #pragma unroll
    for (int k = 0; k < 2; ++k) {
        int x = bx + 2 * tx2 + k, y = by + ty;
        float sx = ((float)x - cx - txf) / sc + cx;
        float sy = ((float)y - cy - tyf) / sc + cy;
        float sxl = sx - (float)rx0, syl = sy - (float)ry0;
        float x0f = floorf(sxl), y0f = floorf(syl);
        float wx = sxl - x0f, wy = syl - y0f;
        int xi = min(max((int)x0f, 0), RPW - 2);
        int yi = min(max((int)y0f, 0), RPH - 2);
        float w00 = (1.f - wx) * (1.f - wy);
        float w10 = wx * (1.f - wy);
        float w01 = (1.f - wx) * wy;
        float w11 = wx * wy;
        int base = yi * RPW + xi;
        float4 v00 = tile[base], v10 = tile[base + 1];
        float4 v01 = tile[base + RPW], v11 = tile[base + RPW + 1];
        float r  = w00 * v00.x + w10 * v10.x + w01 * v01.x + w11 * v11.x;
        float g  = w00 * v00.y + w10 * v10.y + w01 * v01.y + w11 * v11.y;
        float b2 = w00 * v00.z + w10 * v10.z + w01 * v01.z + w11 * v11.z;
        float m  = w00 * v00.w + w10 * v10.w + w01 * v01.w + w11 * v11.w;
        r = clip01(r * bf);
        g = clip01(g * bf);
        b2 = clip01(b2 * bf);
        rr[k] = r; gg[k] = g; bb[k] = b2; mm[k] = m;
        grays += 0.299f * r + 0.587f * g + 0.114f * b2;
    }
    {
        size_t po = (size_t)b * 3 * PLANE + (size_t)(by + ty) * Wd + bx + 2 * tx2;
        *(float2*)(oimgs + po)             = make_float2(rr[0], rr[1]);
        *(float2*)(oimgs + po + PLANE)     = make_float2(gg[0], gg[1]);
        *(float2*)(oimgs + po + 2 * PLANE) = make_float2(bb[0], bb[1]);
        *(float2*)(omasks + (size_t)b * PLANE + (size_t)(by + ty) * Wd + bx + 2 * tx2)
            = make_float2(mm[0], mm[1]);
    }

    __syncthreads();                       // tile reads done; reuse as scratch
    float* sred = (float*)tile;
    sred[tid] = grays;
    __syncthreads();
    for (int off = 128; off > 0; off >>= 1) {
        if (tid < off) sred[tid] += sred[tid + off];
        __syncthreads();
    }
    if (tid == 0)
        partials[(size_t)b * 512 + blockIdx.y * 16 + blockIdx.x] = sred[0];
}

__global__ __launch_bounds__(256) void k_mean(const float* __restrict__ partials,
                                              float* __restrict__ means)
{
    int b = blockIdx.x;
    int t = threadIdx.x;
    float s = partials[(size_t)b * 512 + t] + partials[(size_t)b * 512 + t + 256];
    __shared__ float sr[256];
    sr[t] = s;
    __syncthreads();
    for (int off = 128; off > 0; off >>= 1) {
        if (t < off) sr[t] += sr[t + off];
        __syncthreads();
    }
    if (t == 0) means[b] = sr[0] * (1.f / (float)PLANE);
}

// per-pixel contrast -> saturation -> hue
__device__ __forceinline__ void jit1(float& r, float& g, float& bl,
                                     float mean, float cf, float sf, float hsh)
{
    r  = clip01(cf * r + (1.f - cf) * mean);
    g  = clip01(cf * g + (1.f - cf) * mean);
    bl = clip01(cf * bl + (1.f - cf) * mean);

    float gray = 0.299f * r + 0.587f * g + 0.114f * bl;
    r  = clip01(sf * r + (1.f - sf) * gray);
    g  = clip01(sf * g + (1.f - sf) * gray);
    bl = clip01(sf * bl + (1.f - sf) * gray);

    float maxc = fmaxf(fmaxf(r, g), bl);
    float minc = fminf(fminf(r, g), bl);
    float delta = maxc - minc;
    float sgm = delta / (maxc + 1e-8f);
    float dd = delta + 1e-8f;
    float rc = (maxc - r) / dd;
    float gc = (maxc - g) / dd;
    float bc = (maxc - bl) / dd;
    float h6 = (maxc == r) ? (bc - gc) : ((maxc == g) ? (2.f + rc - bc) : (4.f + gc - rc));
    float h = h6 * (1.f / 6.f);
    h = h - floorf(h);
    h = h + hsh;
    h = h - floorf(h);

    float hi = floorf(h * 6.f);
    float f = h * 6.f - hi;
    float v = maxc;
    float p = v * (1.f - sgm);
    float q = v * (1.f - f * sgm);
    float t = v * (1.f - (1.f - f) * sgm);
    int i = ((int)hi) % 6;
    if (i < 0) i += 6;
    float ro, go, bo;
    switch (i) {
        case 0: ro = v; go = t; bo = p; break;
        case 1: ro = q; go = v; bo = p; break;
        case 2: ro = p; go = v; bo = t; break;
        case 3: ro = p; go = q; bo = v; break;
        case 4: ro = t; go = p; bo = v; break;
        default: ro = v; go = p; bo = q; break;
    }
    r = clip01(ro); g = clip01(go); bl = clip01(bo);
}

__global__ __launch_bounds__(256) void k_jitter(float* __restrict__ oimgs,
                                                const float* __restrict__ means,
                                                const float* __restrict__ contrast,
                                                const float* __restrict__ saturation,
                                                const float* __restrict__ hue)
{
    int b = blockIdx.y;
    size_t i4 = (size_t)blockIdx.x * 256 + threadIdx.x;   // 0..PLANE/4-1
    size_t po = (size_t)b * 3 * PLANE + i4 * 4;
    float4 R  = *(float4*)(oimgs + po);
    float4 G  = *(float4*)(oimgs + po + PLANE);
    float4 Bv = *(float4*)(oimgs + po + 2 * PLANE);

    float mean = means[b];
    float cf = contrast[b], sf = saturation[b], hsh = hue[b];

    jit1(R.x, G.x, Bv.x, mean, cf, sf, hsh);
    jit1(R.y, G.y, Bv.y, mean, cf, sf, hsh);
    jit1(R.z, G.z, Bv.z, mean, cf, sf, hsh);
    jit1(R.w, G.w, Bv.w, mean, cf, sf, hsh);

    *(float4*)(oimgs + po)             = R;
    *(float4*)(oimgs + po + PLANE)     = G;
    *(float4*)(oimgs + po + 2 * PLANE) = Bv;
}

extern "C" void kernel_launch(void* const* d_in, const int* in_sizes, int n_in,
                              void* d_out, int out_size, void* d_ws, size_t ws_size,
                              hipStream_t stream)
{
    const float* imgs       = (const float*)d_in[0];
    const float* masks      = (const float*)d_in[1];
    const int*   hflip      = (const int*)d_in[2];
    const int*   vflip      = (const int*)d_in[3];
    const float* angles     = (const float*)d_in[4];
    const float* translate  = (const float*)d_in[5];
    const float* scale      = (const float*)d_in[6];
    const float* brightness = (const float*)d_in[7];
    const float* contrast   = (const float*)d_in[8];
    const float* saturation = (const float*)d_in[9];
    const float* hue        = (const float*)d_in[10];

    float* oimgs  = (float*)d_out;
    float* omasks = oimgs + (size_t)Bd * 3 * PLANE;

    float4* rot     = (float4*)d_ws;                             // Bd*PLANE float4
    float* partials = (float*)d_ws + (size_t)4 * Bd * PLANE;     // Bd*512
    float* means    = partials + (size_t)Bd * 512;               // Bd

    dim3 blk1(32, 8);
    dim3 grd1(Wd / 32, Hd / 16, Bd);
    k_rotate<<<grd1, blk1, 0, stream>>>(imgs, masks, hflip, vflip, angles, rot);

    dim3 blk2(16, 16);
    dim3 grd2(Wd / 32, Hd / 16, Bd);
    k_affine<<<grd2, blk2, 0, stream>>>(rot, translate, scale, brightness,
                                        oimgs, omasks, partials);

    k_mean<<<Bd, 256, 0, stream>>>(partials, means);

    dim3 grd3(PLANE / 4 / 256, Bd);
    k_jitter<<<grd3, 256, 0, stream>>>(oimgs, means, contrast, saturation, hue);
}

// Round 5
// 181.796 us; speedup vs baseline: 1.2181x; 1.2181x over previous
//
#include <hip/hip_runtime.h>
#include <math.h>

#define Wd 512
#define Hd 512
#define Bd 32
#define PLANE (Hd * Wd)

// k_rotate: 16x16 output tile; rotated-source window <= 15*sqrt(2)+5 -> 26.
// LDS row stride 27 (odd) to decorrelate banks. 26*27*16B = 11232 B.
#define WND 26
#define STR 27

// k_affine staging window (AoS float4 cells); scale>=0.9 -> cols<=39, rows<=21
#define RPW 40
#define RPH 22

__device__ __forceinline__ float clip01(float x) { return fminf(fmaxf(x, 0.f), 1.f); }

// ---------------------------------------------------------------------------
// K1: flip + rotate -> AoS float4 intermediate in ws.
// 16x16 tile, 256 threads, 1 px/thread. Fixed 26x26 window staged zero-padded
// (flips folded into the gather index), 4x ds_read_b128 bilinear sampling.
// ---------------------------------------------------------------------------
__global__ __launch_bounds__(256) void k_rotate(const float* __restrict__ imgs,
                                                const float* __restrict__ masks,
                                                const int* __restrict__ hflip,
                                                const int* __restrict__ vflip,
                                                const float* __restrict__ angles,
                                                float4* __restrict__ rot)
{
    __shared__ float4 tile[WND * STR];

    const int tx = threadIdx.x, ty = threadIdx.y;
    const int tid = ty * 16 + tx;
    const int bx = blockIdx.x * 16, by = blockIdx.y * 16;
    const int b = blockIdx.z;

    const float cx = (Wd - 1) * 0.5f, cy = (Hd - 1) * 0.5f;
    const float th = angles[b] * 0.017453292519943295f;
    const float c = cosf(th), s = sinf(th);
    const bool hf = hflip[b] > 0, vf = vflip[b] > 0;

    // window origin from tile-corner bbox (same fp expression as per-pixel)
    const float xs0 = (float)bx - cx, xs1 = (float)(bx + 15) - cx;
    const float ys0 = (float)by - cy, ys1 = (float)(by + 15) - cy;
    float a0 = c * xs0 + s * ys0 + cx, a1 = c * xs1 + s * ys0 + cx;
    float a2 = c * xs0 + s * ys1 + cx, a3 = c * xs1 + s * ys1 + cx;
    float b0 = -s * xs0 + c * ys0 + cy, b1 = -s * xs1 + c * ys0 + cy;
    float b2 = -s * xs0 + c * ys1 + cy, b3 = -s * xs1 + c * ys1 + cy;
    const int ox0 = (int)floorf(fminf(fminf(a0, a1), fminf(a2, a3))) - 1;
    const int oy0 = (int)floorf(fminf(fminf(b0, b1), fminf(b2, b3))) - 1;

    const float* ib = imgs + (size_t)b * 3 * PLANE;
    const float* mb = masks + (size_t)b * PLANE;

    // stage fixed 26x26 window (+1 pad col), zero outside image, flips folded
    for (int idx = tid; idx < WND * STR; idx += 256) {
        int row = idx / STR;
        int col = idx - row * STR;
        int gy = oy0 + row, gx = ox0 + col;
        float4 v = make_float4(0.f, 0.f, 0.f, 0.f);
        if (col < WND && (unsigned)gy < (unsigned)Hd && (unsigned)gx < (unsigned)Wd) {
            int fy = vf ? (Hd - 1 - gy) : gy;
            int fx = hf ? (Wd - 1 - gx) : gx;
            int gi = fy * Wd + fx;
            v.x = ib[gi];
            v.y = ib[gi + PLANE];
            v.z = ib[gi + 2 * PLANE];
            v.w = mb[gi];
        }
        tile[idx] = v;
    }
    __syncthreads();

    const int x = bx + tx, y = by + ty;
    float dx = (float)x - cx, dy = (float)y - cy;
    float sx = c * dx + s * dy + cx;
    float sy = -s * dx + c * dy + cy;
    float sxl = sx - (float)ox0;
    float syl = sy - (float)oy0;
    float x0f = floorf(sxl), y0f = floorf(syl);
    float wx = sxl - x0f, wy = syl - y0f;
    int xi = min(max((int)x0f, 0), WND - 2);
    int yi = min(max((int)y0f, 0), WND - 2);
    float w00 = (1.f - wx) * (1.f - wy);
    float w10 = wx * (1.f - wy);
    float w01 = (1.f - wx) * wy;
    float w11 = wx * wy;
    int base = yi * STR + xi;
    float4 v00 = tile[base], v10 = tile[base + 1];
    float4 v01 = tile[base + STR], v11 = tile[base + STR + 1];

    float4 o;
    o.x = w00 * v00.x + w10 * v10.x + w01 * v01.x + w11 * v11.x;
    o.y = w00 * v00.y + w10 * v10.y + w01 * v01.y + w11 * v11.y;
    o.z = w00 * v00.z + w10 * v10.z + w01 * v01.z + w11 * v11.z;
    o.w = w00 * v00.w + w10 * v10.w + w01 * v01.w + w11 * v11.w;

    rot[(size_t)b * PLANE + (size_t)y * Wd + x] = o;
}

// ---------------------------------------------------------------------------
// K2: affine from AoS intermediate + brightness -> planar d_out + gray partials.
// 32x16 tile, block (16,16), 2px/thread along x (float2 stores).
// ---------------------------------------------------------------------------
__global__ __launch_bounds__(256) void k_affine(const float4* __restrict__ rot,
                                                const float* __restrict__ translate,
                                                const float* __restrict__ scale,
                                                const float* __restrict__ brightness,
                                                float* __restrict__ oimgs,
                                                float* __restrict__ omasks,
                                                float* __restrict__ partials)
{
    __shared__ float4 tile[RPH * RPW];     // 14080 B

    const int tx2 = threadIdx.x;           // 0..15
    const int ty  = threadIdx.y;           // 0..15
    const int tid = ty * 16 + tx2;
    const int bx = blockIdx.x * 32, by = blockIdx.y * 16;
    const int b = blockIdx.z;

    const float cx = (Wd - 1) * 0.5f, cy = (Hd - 1) * 0.5f;
    const float txf = translate[2 * b] * (float)Wd;
    const float tyf = translate[2 * b + 1] * (float)Hd;
    const float sc = scale[b];
    const float bf = brightness[b];

    float ax0 = ((float)bx - cx - txf) / sc + cx;
    float ax1 = ((float)(bx + 31) - cx - txf) / sc + cx;
    float ay0 = ((float)by - cy - tyf) / sc + cy;
    float ay1 = ((float)(by + 15) - cy - tyf) / sc + cy;
    const int rx0 = (int)floorf(fminf(ax0, ax1)) - 1;
    const int ry0 = (int)floorf(fminf(ay0, ay1)) - 1;

    const float4* src = rot + (size_t)b * PLANE;
    const bool fastp = (rx0 >= 0) && (ry0 >= 0) &&
                       (rx0 + RPW <= Wd) && (ry0 + RPH <= Hd);

    if (fastp) {
        for (int idx = tid; idx < RPH * RPW; idx += 256) {
            int row = idx / RPW;
            int col = idx - row * RPW;
            tile[idx] = src[(ry0 + row) * Wd + rx0 + col];
        }
    } else {
        for (int idx = tid; idx < RPH * RPW; idx += 256) {
            int row = idx / RPW;
            int col = idx - row * RPW;
            int gy = ry0 + row, gx = rx0 + col;
            float4 v = make_float4(0.f, 0.f, 0.f, 0.f);
            if ((unsigned)gy < (unsigned)Hd && (unsigned)gx < (unsigned)Wd)
                v = src[gy * Wd + gx];
            tile[idx] = v;
        }
    }
    __syncthreads();

    float grays = 0.f;
    float rr[2], gg[2], bb[2], mm[2];
    #pragma unroll
    for (int k = 0; k < 2; ++k) {
        int x = bx + 2 * tx2 + k, y = by + ty;
        float sx = ((float)x - cx - txf) / sc + cx;
        float sy = ((float)y - cy - tyf) / sc + cy;
        float sxl = sx - (float)rx0, syl = sy - (float)ry0;
        float x0f = floorf(sxl), y0f = floorf(syl);
        float wx = sxl - x0f, wy = syl - y0f;
        int xi = min(max((int)x0f, 0), RPW - 2);
        int yi = min(max((int)y0f, 0), RPH - 2);
        float w00 = (1.f - wx) * (1.f - wy);
        float w10 = wx * (1.f - wy);
        float w01 = (1.f - wx) * wy;
        float w11 = wx * wy;
        int base = yi * RPW + xi;
        float4 v00 = tile[base], v10 = tile[base + 1];
        float4 v01 = tile[base + RPW], v11 = tile[base + RPW + 1];
        float r  = w00 * v00.x + w10 * v10.x + w01 * v01.x + w11 * v11.x;
        float g  = w00 * v00.y + w10 * v10.y + w01 * v01.y + w11 * v11.y;
        float b2 = w00 * v00.z + w10 * v10.z + w01 * v01.z + w11 * v11.z;
        float m  = w00 * v00.w + w10 * v10.w + w01 * v01.w + w11 * v11.w;
        r = clip01(r * bf);
        g = clip01(g * bf);
        b2 = clip01(b2 * bf);
        rr[k] = r; gg[k] = g; bb[k] = b2; mm[k] = m;
        grays += 0.299f * r + 0.587f * g + 0.114f * b2;
    }
    {
        size_t po = (size_t)b * 3 * PLANE + (size_t)(by + ty) * Wd + bx + 2 * tx2;
        *(float2*)(oimgs + po)             = make_float2(rr[0], rr[1]);
        *(float2*)(oimgs + po + PLANE)     = make_float2(gg[0], gg[1]);
        *(float2*)(oimgs + po + 2 * PLANE) = make_float2(bb[0], bb[1]);
        *(float2*)(omasks + (size_t)b * PLANE + (size_t)(by + ty) * Wd + bx + 2 * tx2)
            = make_float2(mm[0], mm[1]);
    }

    __syncthreads();
    float* sred = (float*)tile;
    sred[tid] = grays;
    __syncthreads();
    for (int off = 128; off > 0; off >>= 1) {
        if (tid < off) sred[tid] += sred[tid + off];
        __syncthreads();
    }
    if (tid == 0)
        partials[(size_t)b * 512 + blockIdx.y * 16 + blockIdx.x] = sred[0];
}

__global__ __launch_bounds__(256) void k_mean(const float* __restrict__ partials,
                                              float* __restrict__ means)
{
    int b = blockIdx.x;
    int t = threadIdx.x;
    float s = partials[(size_t)b * 512 + t] + partials[(size_t)b * 512 + t + 256];
    __shared__ float sr[256];
    sr[t] = s;
    __syncthreads();
    for (int off = 128; off > 0; off >>= 1) {
        if (t < off) sr[t] += sr[t + off];
        __syncthreads();
    }
    if (t == 0) means[b] = sr[0] * (1.f / (float)PLANE);
}

__device__ __forceinline__ void jit1(float& r, float& g, float& bl,
                                     float mean, float cf, float sf, float hsh)
{
    r  = clip01(cf * r + (1.f - cf) * mean);
    g  = clip01(cf * g + (1.f - cf) * mean);
    bl = clip01(cf * bl + (1.f - cf) * mean);

    float gray = 0.299f * r + 0.587f * g + 0.114f * bl;
    r  = clip01(sf * r + (1.f - sf) * gray);
    g  = clip01(sf * g + (1.f - sf) * gray);
    bl = clip01(sf * bl + (1.f - sf) * gray);

    float maxc = fmaxf(fmaxf(r, g), bl);
    float minc = fminf(fminf(r, g), bl);
    float delta = maxc - minc;
    float sgm = delta / (maxc + 1e-8f);
    float dd = delta + 1e-8f;
    float rc = (maxc - r) / dd;
    float gc = (maxc - g) / dd;
    float bc = (maxc - bl) / dd;
    float h6 = (maxc == r) ? (bc - gc) : ((maxc == g) ? (2.f + rc - bc) : (4.f + gc - rc));
    float h = h6 * (1.f / 6.f);
    h = h - floorf(h);
    h = h + hsh;
    h = h - floorf(h);

    float hi = floorf(h * 6.f);
    float f = h * 6.f - hi;
    float v = maxc;
    float p = v * (1.f - sgm);
    float q = v * (1.f - f * sgm);
    float t = v * (1.f - (1.f - f) * sgm);
    int i = ((int)hi) % 6;
    if (i < 0) i += 6;
    float ro, go, bo;
    switch (i) {
        case 0: ro = v; go = t; bo = p; break;
        case 1: ro = q; go = v; bo = p; break;
        case 2: ro = p; go = v; bo = t; break;
        case 3: ro = p; go = q; bo = v; break;
        case 4: ro = t; go = p; bo = v; break;
        default: ro = v; go = p; bo = q; break;
    }
    r = clip01(ro); g = clip01(go); bl = clip01(bo);
}

__global__ __launch_bounds__(256) void k_jitter(float* __restrict__ oimgs,
                                                const float* __restrict__ means,
                                                const float* __restrict__ contrast,
                                                const float* __restrict__ saturation,
                                                const float* __restrict__ hue)
{
    int b = blockIdx.y;
    size_t i4 = (size_t)blockIdx.x * 256 + threadIdx.x;
    size_t po = (size_t)b * 3 * PLANE + i4 * 4;
    float4 R  = *(float4*)(oimgs + po);
    float4 G  = *(float4*)(oimgs + po + PLANE);
    float4 Bv = *(float4*)(oimgs + po + 2 * PLANE);

    float mean = means[b];
    float cf = contrast[b], sf = saturation[b], hsh = hue[b];

    jit1(R.x, G.x, Bv.x, mean, cf, sf, hsh);
    jit1(R.y, G.y, Bv.y, mean, cf, sf, hsh);
    jit1(R.z, G.z, Bv.z, mean, cf, sf, hsh);
    jit1(R.w, G.w, Bv.w, mean, cf, sf, hsh);

    *(float4*)(oimgs + po)             = R;
    *(float4*)(oimgs + po + PLANE)     = G;
    *(float4*)(oimgs + po + 2 * PLANE) = Bv;
}

extern "C" void kernel_launch(void* const* d_in, const int* in_sizes, int n_in,
                              void* d_out, int out_size, void* d_ws, size_t ws_size,
                              hipStream_t stream)
{
    const float* imgs       = (const float*)d_in[0];
    const float* masks      = (const float*)d_in[1];
    const int*   hflip      = (const int*)d_in[2];
    const int*   vflip      = (const int*)d_in[3];
    const float* angles     = (const float*)d_in[4];
    const float* translate  = (const float*)d_in[5];
    const float* scale      = (const float*)d_in[6];
    const float* brightness = (const float*)d_in[7];
    const float* contrast   = (const float*)d_in[8];
    const float* saturation = (const float*)d_in[9];
    const float* hue        = (const float*)d_in[10];

    float* oimgs  = (float*)d_out;
    float* omasks = oimgs + (size_t)Bd * 3 * PLANE;

    float4* rot     = (float4*)d_ws;                             // Bd*PLANE float4
    float* partials = (float*)d_ws + (size_t)4 * Bd * PLANE;     // Bd*512
    float* means    = partials + (size_t)Bd * 512;               // Bd

    dim3 blk1(16, 16);
    dim3 grd1(Wd / 16, Hd / 16, Bd);
    k_rotate<<<grd1, blk1, 0, stream>>>(imgs, masks, hflip, vflip, angles, rot);

    dim3 blk2(16, 16);
    dim3 grd2(Wd / 32, Hd / 16, Bd);
    k_affine<<<grd2, blk2, 0, stream>>>(rot, translate, scale, brightness,
                                        oimgs, omasks, partials);

    k_mean<<<Bd, 256, 0, stream>>>(partials, means);

    dim3 grd3(PLANE / 4 / 256, Bd);
    k_jitter<<<grd3, 256, 0, stream>>>(oimgs, means, contrast, saturation, hue);
}

// Round 6
// 151.678 us; speedup vs baseline: 1.4599x; 1.1986x over previous
//
#include <hip/hip_runtime.h>
#include <hip/hip_fp16.h>
#include <math.h>

#define Wd 512
#define Hd 512
#define Bd 32
#define PLANE (Hd * Wd)

// k_rotate: 16x16 output tile; rotated-source window <= 15*sqrt(2)+5 -> 26.
// LDS row stride 27 (odd) to decorrelate banks. 26*27*16B = 11232 B.
#define WND 26
#define STR 27

// k_affine staging window (AoS float4 cells); scale>=0.9 -> cols<=39, rows<=21
#define RPW 40
#define RPH 22

__device__ __forceinline__ float clip01(float x) { return fminf(fmaxf(x, 0.f), 1.f); }

// ---------------------------------------------------------------------------
// K1: flip + rotate -> packed-half AoS intermediate (ushort4 = 4 x fp16) in ws.
// 16x16 tile, 256 threads, 1 px/thread. Fixed 26x26 window staged zero-padded
// (flips folded into the gather index), 4x ds_read_b128 bilinear sampling.
// ---------------------------------------------------------------------------
__global__ __launch_bounds__(256) void k_rotate(const float* __restrict__ imgs,
                                                const float* __restrict__ masks,
                                                const int* __restrict__ hflip,
                                                const int* __restrict__ vflip,
                                                const float* __restrict__ angles,
                                                ushort4* __restrict__ rot)
{
    __shared__ float4 tile[WND * STR];

    const int tx = threadIdx.x, ty = threadIdx.y;
    const int tid = ty * 16 + tx;
    const int bx = blockIdx.x * 16, by = blockIdx.y * 16;
    const int b = blockIdx.z;

    const float cx = (Wd - 1) * 0.5f, cy = (Hd - 1) * 0.5f;
    const float th = angles[b] * 0.017453292519943295f;
    const float c = cosf(th), s = sinf(th);
    const bool hf = hflip[b] > 0, vf = vflip[b] > 0;

    // window origin from tile-corner bbox (same fp expression as per-pixel)
    const float xs0 = (float)bx - cx, xs1 = (float)(bx + 15) - cx;
    const float ys0 = (float)by - cy, ys1 = (float)(by + 15) - cy;
    float a0 = c * xs0 + s * ys0 + cx, a1 = c * xs1 + s * ys0 + cx;
    float a2 = c * xs0 + s * ys1 + cx, a3 = c * xs1 + s * ys1 + cx;
    float b0 = -s * xs0 + c * ys0 + cy, b1 = -s * xs1 + c * ys0 + cy;
    float b2 = -s * xs0 + c * ys1 + cy, b3 = -s * xs1 + c * ys1 + cy;
    const int ox0 = (int)floorf(fminf(fminf(a0, a1), fminf(a2, a3))) - 1;
    const int oy0 = (int)floorf(fminf(fminf(b0, b1), fminf(b2, b3))) - 1;

    const float* ib = imgs + (size_t)b * 3 * PLANE;
    const float* mb = masks + (size_t)b * PLANE;

    // stage fixed 26x26 window (+1 pad col), zero outside image, flips folded
    for (int idx = tid; idx < WND * STR; idx += 256) {
        int row = idx / STR;
        int col = idx - row * STR;
        int gy = oy0 + row, gx = ox0 + col;
        float4 v = make_float4(0.f, 0.f, 0.f, 0.f);
        if (col < WND && (unsigned)gy < (unsigned)Hd && (unsigned)gx < (unsigned)Wd) {
            int fy = vf ? (Hd - 1 - gy) : gy;
            int fx = hf ? (Wd - 1 - gx) : gx;
            int gi = fy * Wd + fx;
            v.x = ib[gi];
            v.y = ib[gi + PLANE];
            v.z = ib[gi + 2 * PLANE];
            v.w = mb[gi];
        }
        tile[idx] = v;
    }
    __syncthreads();

    const int x = bx + tx, y = by + ty;
    float dx = (float)x - cx, dy = (float)y - cy;
    float sx = c * dx + s * dy + cx;
    float sy = -s * dx + c * dy + cy;
    float sxl = sx - (float)ox0;
    float syl = sy - (float)oy0;
    float x0f = floorf(sxl), y0f = floorf(syl);
    float wx = sxl - x0f, wy = syl - y0f;
    int xi = min(max((int)x0f, 0), WND - 2);
    int yi = min(max((int)y0f, 0), WND - 2);
    float w00 = (1.f - wx) * (1.f - wy);
    float w10 = wx * (1.f - wy);
    float w01 = (1.f - wx) * wy;
    float w11 = wx * wy;
    int base = yi * STR + xi;
    float4 v00 = tile[base], v10 = tile[base + 1];
    float4 v01 = tile[base + STR], v11 = tile[base + STR + 1];

    float r  = w00 * v00.x + w10 * v10.x + w01 * v01.x + w11 * v11.x;
    float g  = w00 * v00.y + w10 * v10.y + w01 * v01.y + w11 * v11.y;
    float b2v = w00 * v00.z + w10 * v10.z + w01 * v01.z + w11 * v11.z;
    float m  = w00 * v00.w + w10 * v10.w + w01 * v01.w + w11 * v11.w;

    ushort4 o;
    o.x = __half_as_ushort(__float2half(r));
    o.y = __half_as_ushort(__float2half(g));
    o.z = __half_as_ushort(__float2half(b2v));
    o.w = __half_as_ushort(__float2half(m));
    rot[(size_t)b * PLANE + (size_t)y * Wd + x] = o;
}

// ---------------------------------------------------------------------------
// K2: affine from packed-half intermediate + brightness -> planar d_out +
// gray partials. 32x16 tile, block (16,16), 2px/thread along x.
// LDS tile is float4 (converted during staging) so sampling is ds_read_b128.
// ---------------------------------------------------------------------------
__global__ __launch_bounds__(256) void k_affine(const ushort4* __restrict__ rot,
                                                const float* __restrict__ translate,
                                                const float* __restrict__ scale,
                                                const float* __restrict__ brightness,
                                                float* __restrict__ oimgs,
                                                float* __restrict__ omasks,
                                                float* __restrict__ partials)
{
    __shared__ float4 tile[RPH * RPW];     // 14080 B

    const int tx2 = threadIdx.x;           // 0..15
    const int ty  = threadIdx.y;           // 0..15
    const int tid = ty * 16 + tx2;
    const int bx = blockIdx.x * 32, by = blockIdx.y * 16;
    const int b = blockIdx.z;

    const float cx = (Wd - 1) * 0.5f, cy = (Hd - 1) * 0.5f;
    const float txf = translate[2 * b] * (float)Wd;
    const float tyf = translate[2 * b + 1] * (float)Hd;
    const float sc = scale[b];
    const float bf = brightness[b];

    float ax0 = ((float)bx - cx - txf) / sc + cx;
    float ax1 = ((float)(bx + 31) - cx - txf) / sc + cx;
    float ay0 = ((float)by - cy - tyf) / sc + cy;
    float ay1 = ((float)(by + 15) - cy - tyf) / sc + cy;
    const int rx0 = (int)floorf(fminf(ax0, ax1)) - 1;
    const int ry0 = (int)floorf(fminf(ay0, ay1)) - 1;

    const ushort4* src = rot + (size_t)b * PLANE;
    const bool fastp = (rx0 >= 0) && (ry0 >= 0) &&
                       (rx0 + RPW <= Wd) && (ry0 + RPH <= Hd);

    if (fastp) {
        for (int idx = tid; idx < RPH * RPW; idx += 256) {
            int row = idx / RPW;
            int col = idx - row * RPW;
            ushort4 h = src[(ry0 + row) * Wd + rx0 + col];
            tile[idx] = make_float4(__half2float(__ushort_as_half(h.x)),
                                    __half2float(__ushort_as_half(h.y)),
                                    __half2float(__ushort_as_half(h.z)),
                                    __half2float(__ushort_as_half(h.w)));
        }
    } else {
        for (int idx = tid; idx < RPH * RPW; idx += 256) {
            int row = idx / RPW;
            int col = idx - row * RPW;
            int gy = ry0 + row, gx = rx0 + col;
            float4 v = make_float4(0.f, 0.f, 0.f, 0.f);
            if ((unsigned)gy < (unsigned)Hd && (unsigned)gx < (unsigned)Wd) {
                ushort4 h = src[gy * Wd + gx];
                v = make_float4(__half2float(__ushort_as_half(h.x)),
                                __half2float(__ushort_as_half(h.y)),
                                __half2float(__ushort_as_half(h.z)),
                                __half2float(__ushort_as_half(h.w)));
            }
            tile[idx] = v;
        }
    }
    __syncthreads();

    float grays = 0.f;
    float rr[2], gg[2], bb[2], mm[2];
    #pragma unroll
    for (int k = 0; k < 2; ++k) {
        int x = bx + 2 * tx2 + k, y = by + ty;
        float sx = ((float)x - cx - txf) / sc + cx;
        float sy = ((float)y - cy - tyf) / sc + cy;
        float sxl = sx - (float)rx0, syl = sy - (float)ry0;
        float x0f = floorf(sxl), y0f = floorf(syl);
        float wx = sxl - x0f, wy = syl - y0f;
        int xi = min(max((int)x0f, 0), RPW - 2);
        int yi = min(max((int)y0f, 0), RPH - 2);
        float w00 = (1.f - wx) * (1.f - wy);
        float w10 = wx * (1.f - wy);
        float w01 = (1.f - wx) * wy;
        float w11 = wx * wy;
        int base = yi * RPW + xi;
        float4 v00 = tile[base], v10 = tile[base + 1];
        float4 v01 = tile[base + RPW], v11 = tile[base + RPW + 1];
        float r  = w00 * v00.x + w10 * v10.x + w01 * v01.x + w11 * v11.x;
        float g  = w00 * v00.y + w10 * v10.y + w01 * v01.y + w11 * v11.y;
        float b2 = w00 * v00.z + w10 * v10.z + w01 * v01.z + w11 * v11.z;
        float m  = w00 * v00.w + w10 * v10.w + w01 * v01.w + w11 * v11.w;
        r = clip01(r * bf);
        g = clip01(g * bf);
        b2 = clip01(b2 * bf);
        rr[k] = r; gg[k] = g; bb[k] = b2; mm[k] = m;
        grays += 0.299f * r + 0.587f * g + 0.114f * b2;
    }
    {
        size_t po = (size_t)b * 3 * PLANE + (size_t)(by + ty) * Wd + bx + 2 * tx2;
        *(float2*)(oimgs + po)             = make_float2(rr[0], rr[1]);
        *(float2*)(oimgs + po + PLANE)     = make_float2(gg[0], gg[1]);
        *(float2*)(oimgs + po + 2 * PLANE) = make_float2(bb[0], bb[1]);
        *(float2*)(omasks + (size_t)b * PLANE + (size_t)(by + ty) * Wd + bx + 2 * tx2)
            = make_float2(mm[0], mm[1]);
    }

    __syncthreads();
    float* sred = (float*)tile;
    sred[tid] = grays;
    __syncthreads();
    for (int off = 128; off > 0; off >>= 1) {
        if (tid < off) sred[tid] += sred[tid + off];
        __syncthreads();
    }
    if (tid == 0)
        partials[(size_t)b * 512 + blockIdx.y * 16 + blockIdx.x] = sred[0];
}

__global__ __launch_bounds__(256) void k_mean(const float* __restrict__ partials,
                                              float* __restrict__ means)
{
    int b = blockIdx.x;
    int t = threadIdx.x;
    float s = partials[(size_t)b * 512 + t] + partials[(size_t)b * 512 + t + 256];
    __shared__ float sr[256];
    sr[t] = s;
    __syncthreads();
    for (int off = 128; off > 0; off >>= 1) {
        if (t < off) sr[t] += sr[t + off];
        __syncthreads();
    }
    if (t == 0) means[b] = sr[0] * (1.f / (float)PLANE);
}

__device__ __forceinline__ void jit1(float& r, float& g, float& bl,
                                     float mean, float cf, float sf, float hsh)
{
    r  = clip01(cf * r + (1.f - cf) * mean);
    g  = clip01(cf * g + (1.f - cf) * mean);
    bl = clip01(cf * bl + (1.f - cf) * mean);

    float gray = 0.299f * r + 0.587f * g + 0.114f * bl;
    r  = clip01(sf * r + (1.f - sf) * gray);
    g  = clip01(sf * g + (1.f - sf) * gray);
    bl = clip01(sf * bl + (1.f - sf) * gray);

    float maxc = fmaxf(fmaxf(r, g), bl);
    float minc = fminf(fminf(r, g), bl);
    float delta = maxc - minc;
    float sgm = delta / (maxc + 1e-8f);
    float dd = delta + 1e-8f;
    float rc = (maxc - r) / dd;
    float gc = (maxc - g) / dd;
    float bc = (maxc - bl) / dd;
    float h6 = (maxc == r) ? (bc - gc) : ((maxc == g) ? (2.f + rc - bc) : (4.f + gc - rc));
    float h = h6 * (1.f / 6.f);
    h = h - floorf(h);
    h = h + hsh;
    h = h - floorf(h);

    float hi = floorf(h * 6.f);
    float f = h * 6.f - hi;
    float v = maxc;
    float p = v * (1.f - sgm);
    float q = v * (1.f - f * sgm);
    float t = v * (1.f - (1.f - f) * sgm);
    int i = ((int)hi) % 6;
    if (i < 0) i += 6;
    float ro, go, bo;
    switch (i) {
        case 0: ro = v; go = t; bo = p; break;
        case 1: ro = q; go = v; bo = p; break;
        case 2: ro = p; go = v; bo = t; break;
        case 3: ro = p; go = q; bo = v; break;
        case 4: ro = t; go = p; bo = v; break;
        default: ro = v; go = p; bo = q; break;
    }
    r = clip01(ro); g = clip01(go); bl = clip01(bo);
}

__global__ __launch_bounds__(256) void k_jitter(float* __restrict__ oimgs,
                                                const float* __restrict__ means,
                                                const float* __restrict__ contrast,
                                                const float* __restrict__ saturation,
                                                const float* __restrict__ hue)
{
    int b = blockIdx.y;
    size_t i4 = (size_t)blockIdx.x * 256 + threadIdx.x;
    size_t po = (size_t)b * 3 * PLANE + i4 * 4;
    float4 R  = *(float4*)(oimgs + po);
    float4 G  = *(float4*)(oimgs + po + PLANE);
    float4 Bv = *(float4*)(oimgs + po + 2 * PLANE);

    float mean = means[b];
    float cf = contrast[b], sf = saturation[b], hsh = hue[b];

    jit1(R.x, G.x, Bv.x, mean, cf, sf, hsh);
    jit1(R.y, G.y, Bv.y, mean, cf, sf, hsh);
    jit1(R.z, G.z, Bv.z, mean, cf, sf, hsh);
    jit1(R.w, G.w, Bv.w, mean, cf, sf, hsh);

    *(float4*)(oimgs + po)             = R;
    *(float4*)(oimgs + po + PLANE)     = G;
    *(float4*)(oimgs + po + 2 * PLANE) = Bv;
}

extern "C" void kernel_launch(void* const* d_in, const int* in_sizes, int n_in,
                              void* d_out, int out_size, void* d_ws, size_t ws_size,
                              hipStream_t stream)
{
    const float* imgs       = (const float*)d_in[0];
    const float* masks      = (const float*)d_in[1];
    const int*   hflip      = (const int*)d_in[2];
    const int*   vflip      = (const int*)d_in[3];
    const float* angles     = (const float*)d_in[4];
    const float* translate  = (const float*)d_in[5];
    const float* scale      = (const float*)d_in[6];
    const float* brightness = (const float*)d_in[7];
    const float* contrast   = (const float*)d_in[8];
    const float* saturation = (const float*)d_in[9];
    const float* hue        = (const float*)d_in[10];

    float* oimgs  = (float*)d_out;
    float* omasks = oimgs + (size_t)Bd * 3 * PLANE;

    ushort4* rot    = (ushort4*)d_ws;                            // Bd*PLANE*8B
    float* partials = (float*)d_ws + (size_t)2 * Bd * PLANE;     // Bd*512
    float* means    = partials + (size_t)Bd * 512;               // Bd

    dim3 blk1(16, 16);
    dim3 grd1(Wd / 16, Hd / 16, Bd);
    k_rotate<<<grd1, blk1, 0, stream>>>(imgs, masks, hflip, vflip, angles, rot);

    dim3 blk2(16, 16);
    dim3 grd2(Wd / 32, Hd / 16, Bd);
    k_affine<<<grd2, blk2, 0, stream>>>(rot, translate, scale, brightness,
                                        oimgs, omasks, partials);

    k_mean<<<Bd, 256, 0, stream>>>(partials, means);

    dim3 grd3(PLANE / 4 / 256, Bd);
    k_jitter<<<grd3, 256, 0, stream>>>(oimgs, means, contrast, saturation, hue);
}

// Round 7
// 147.312 us; speedup vs baseline: 1.5032x; 1.0296x over previous
//
#include <hip/hip_runtime.h>
#include <hip/hip_fp16.h>
#include <math.h>

#define Wd 512
#define Hd 512
#define Bd 32
#define PLANE (Hd * Wd)

// k_rotate: 16x16 output tile; rotated-source window <= 15*sqrt(2)+5 -> 26.
// LDS row stride 27 (odd) to decorrelate banks. 26*27*16B = 11232 B.
#define WND 26
#define STR 27
#define NCELL (WND * STR)        // 702 = 2*256 + 190

// k_affine staging window (AoS float4 cells); scale>=0.9 -> cols<=39, rows<=21
#define RPW 40
#define RPH 22

__device__ __forceinline__ float clip01(float x) { return fminf(fmaxf(x, 0.f), 1.f); }

__device__ __forceinline__ unsigned pack2h(float a, float b) {
    __half2 h = __floats2half2_rn(a, b);
    return *(unsigned*)&h;
}

// ---------------------------------------------------------------------------
// K1: flip + rotate -> packed-half AoS intermediate (ushort4 = 4 x fp16) in ws.
// 16x16 tile, 1 px/thread. Staging is load-early/write-late: all 12 global
// loads issued into registers before any LDS write (one vmcnt round, not 3).
// ---------------------------------------------------------------------------
__global__ __launch_bounds__(256) void k_rotate(const float* __restrict__ imgs,
                                                const float* __restrict__ masks,
                                                const int* __restrict__ hflip,
                                                const int* __restrict__ vflip,
                                                const float* __restrict__ angles,
                                                ushort4* __restrict__ rot)
{
    __shared__ float4 tile[NCELL];

    const int tx = threadIdx.x, ty = threadIdx.y;
    const int tid = ty * 16 + tx;
    const int bx = blockIdx.x * 16, by = blockIdx.y * 16;
    const int b = blockIdx.z;

    const float cx = (Wd - 1) * 0.5f, cy = (Hd - 1) * 0.5f;
    const float th = angles[b] * 0.017453292519943295f;
    const float c = cosf(th), s = sinf(th);
    const bool hf = hflip[b] > 0, vf = vflip[b] > 0;

    // window origin from tile-corner bbox (same fp expression as per-pixel)
    const float xs0 = (float)bx - cx, xs1 = (float)(bx + 15) - cx;
    const float ys0 = (float)by - cy, ys1 = (float)(by + 15) - cy;
    float a0 = c * xs0 + s * ys0 + cx, a1 = c * xs1 + s * ys0 + cx;
    float a2 = c * xs0 + s * ys1 + cx, a3 = c * xs1 + s * ys1 + cx;
    float b0 = -s * xs0 + c * ys0 + cy, b1 = -s * xs1 + c * ys0 + cy;
    float b2 = -s * xs0 + c * ys1 + cy, b3 = -s * xs1 + c * ys1 + cy;
    const int ox0 = (int)floorf(fminf(fminf(a0, a1), fminf(a2, a3))) - 1;
    const int oy0 = (int)floorf(fminf(fminf(b0, b1), fminf(b2, b3))) - 1;

    const float* ib = imgs + (size_t)b * 3 * PLANE;
    const float* mb = masks + (size_t)b * PLANE;

    // ---- phase 1: issue ALL staging loads into registers ----
    float4 vb[3];
    #pragma unroll
    for (int it = 0; it < 3; ++it) {
        int idx = tid + it * 256;
        float4 v = make_float4(0.f, 0.f, 0.f, 0.f);
        if (idx < NCELL) {
            int row = idx / STR;
            int col = idx - row * STR;
            int gy = oy0 + row, gx = ox0 + col;
            if (col < WND && (unsigned)gy < (unsigned)Hd && (unsigned)gx < (unsigned)Wd) {
                int fy = vf ? (Hd - 1 - gy) : gy;
                int fx = hf ? (Wd - 1 - gx) : gx;
                int gi = fy * Wd + fx;
                v.x = ib[gi];
                v.y = ib[gi + PLANE];
                v.z = ib[gi + 2 * PLANE];
                v.w = mb[gi];
            }
        }
        vb[it] = v;
    }
    // ---- phase 2: LDS writes ----
    #pragma unroll
    for (int it = 0; it < 3; ++it) {
        int idx = tid + it * 256;
        if (idx < NCELL) tile[idx] = vb[it];
    }
    __syncthreads();

    const int x = bx + tx, y = by + ty;
    float dx = (float)x - cx, dy = (float)y - cy;
    float sx = c * dx + s * dy + cx;
    float sy = -s * dx + c * dy + cy;
    float sxl = sx - (float)ox0;
    float syl = sy - (float)oy0;
    float x0f = floorf(sxl), y0f = floorf(syl);
    float wx = sxl - x0f, wy = syl - y0f;
    int xi = min(max((int)x0f, 0), WND - 2);
    int yi = min(max((int)y0f, 0), WND - 2);
    float w00 = (1.f - wx) * (1.f - wy);
    float w10 = wx * (1.f - wy);
    float w01 = (1.f - wx) * wy;
    float w11 = wx * wy;
    int base = yi * STR + xi;
    float4 v00 = tile[base], v10 = tile[base + 1];
    float4 v01 = tile[base + STR], v11 = tile[base + STR + 1];

    float r  = w00 * v00.x + w10 * v10.x + w01 * v01.x + w11 * v11.x;
    float g  = w00 * v00.y + w10 * v10.y + w01 * v01.y + w11 * v11.y;
    float b2v = w00 * v00.z + w10 * v10.z + w01 * v01.z + w11 * v11.z;
    float m  = w00 * v00.w + w10 * v10.w + w01 * v01.w + w11 * v11.w;

    ushort4 o;
    o.x = __half_as_ushort(__float2half(r));
    o.y = __half_as_ushort(__float2half(g));
    o.z = __half_as_ushort(__float2half(b2v));
    o.w = __half_as_ushort(__float2half(m));
    rot[(size_t)b * PLANE + (size_t)y * Wd + x] = o;
}

// ---------------------------------------------------------------------------
// K2: affine from packed-half intermediate + brightness. Writes masks (final)
// to d_out, rgb as packed fp16 planes to ws, and gray partials.
// ---------------------------------------------------------------------------
__global__ __launch_bounds__(256) void k_affine(const ushort4* __restrict__ rot,
                                                const float* __restrict__ translate,
                                                const float* __restrict__ scale,
                                                const float* __restrict__ brightness,
                                                unsigned short* __restrict__ pre,
                                                float* __restrict__ omasks,
                                                float* __restrict__ partials)
{
    __shared__ float4 tile[RPH * RPW];     // 14080 B

    const int tx2 = threadIdx.x;           // 0..15
    const int ty  = threadIdx.y;           // 0..15
    const int tid = ty * 16 + tx2;
    const int bx = blockIdx.x * 32, by = blockIdx.y * 16;
    const int b = blockIdx.z;

    const float cx = (Wd - 1) * 0.5f, cy = (Hd - 1) * 0.5f;
    const float txf = translate[2 * b] * (float)Wd;
    const float tyf = translate[2 * b + 1] * (float)Hd;
    const float sc = scale[b];
    const float bf = brightness[b];

    float ax0 = ((float)bx - cx - txf) / sc + cx;
    float ax1 = ((float)(bx + 31) - cx - txf) / sc + cx;
    float ay0 = ((float)by - cy - tyf) / sc + cy;
    float ay1 = ((float)(by + 15) - cy - tyf) / sc + cy;
    const int rx0 = (int)floorf(fminf(ax0, ax1)) - 1;
    const int ry0 = (int)floorf(fminf(ay0, ay1)) - 1;

    const ushort4* src = rot + (size_t)b * PLANE;
    const bool fastp = (rx0 >= 0) && (ry0 >= 0) &&
                       (rx0 + RPW <= Wd) && (ry0 + RPH <= Hd);

    if (fastp) {
        for (int idx = tid; idx < RPH * RPW; idx += 256) {
            int row = idx / RPW;
            int col = idx - row * RPW;
            ushort4 h = src[(ry0 + row) * Wd + rx0 + col];
            tile[idx] = make_float4(__half2float(__ushort_as_half(h.x)),
                                    __half2float(__ushort_as_half(h.y)),
                                    __half2float(__ushort_as_half(h.z)),
                                    __half2float(__ushort_as_half(h.w)));
        }
    } else {
        for (int idx = tid; idx < RPH * RPW; idx += 256) {
            int row = idx / RPW;
            int col = idx - row * RPW;
            int gy = ry0 + row, gx = rx0 + col;
            float4 v = make_float4(0.f, 0.f, 0.f, 0.f);
            if ((unsigned)gy < (unsigned)Hd && (unsigned)gx < (unsigned)Wd) {
                ushort4 h = src[gy * Wd + gx];
                v = make_float4(__half2float(__ushort_as_half(h.x)),
                                __half2float(__ushort_as_half(h.y)),
                                __half2float(__ushort_as_half(h.z)),
                                __half2float(__ushort_as_half(h.w)));
            }
            tile[idx] = v;
        }
    }
    __syncthreads();

    float grays = 0.f;
    float rr[2], gg[2], bb[2], mm[2];
    #pragma unroll
    for (int k = 0; k < 2; ++k) {
        int x = bx + 2 * tx2 + k, y = by + ty;
        float sx = ((float)x - cx - txf) / sc + cx;
        float sy = ((float)y - cy - tyf) / sc + cy;
        float sxl = sx - (float)rx0, syl = sy - (float)ry0;
        float x0f = floorf(sxl), y0f = floorf(syl);
        float wx = sxl - x0f, wy = syl - y0f;
        int xi = min(max((int)x0f, 0), RPW - 2);
        int yi = min(max((int)y0f, 0), RPH - 2);
        float w00 = (1.f - wx) * (1.f - wy);
        float w10 = wx * (1.f - wy);
        float w01 = (1.f - wx) * wy;
        float w11 = wx * wy;
        int base = yi * RPW + xi;
        float4 v00 = tile[base], v10 = tile[base + 1];
        float4 v01 = tile[base + RPW], v11 = tile[base + RPW + 1];
        float r  = w00 * v00.x + w10 * v10.x + w01 * v01.x + w11 * v11.x;
        float g  = w00 * v00.y + w10 * v10.y + w01 * v01.y + w11 * v11.y;
        float b2 = w00 * v00.z + w10 * v10.z + w01 * v01.z + w11 * v11.z;
        float m  = w00 * v00.w + w10 * v10.w + w01 * v01.w + w11 * v11.w;
        r = clip01(r * bf);
        g = clip01(g * bf);
        b2 = clip01(b2 * bf);
        rr[k] = r; gg[k] = g; bb[k] = b2; mm[k] = m;
        grays += 0.299f * r + 0.587f * g + 0.114f * b2;
    }
    {
        // fp16 rgb planes to ws (packed pairs), masks final to d_out
        size_t pix = (size_t)(by + ty) * Wd + bx + 2 * tx2;       // even
        unsigned short* pb = pre + (size_t)b * 3 * PLANE;
        *(unsigned*)(pb + pix)             = pack2h(rr[0], rr[1]);
        *(unsigned*)(pb + PLANE + pix)     = pack2h(gg[0], gg[1]);
        *(unsigned*)(pb + 2 * PLANE + pix) = pack2h(bb[0], bb[1]);
        *(float2*)(omasks + (size_t)b * PLANE + pix) = make_float2(mm[0], mm[1]);
    }

    __syncthreads();
    float* sred = (float*)tile;
    sred[tid] = grays;
    __syncthreads();
    for (int off = 128; off > 0; off >>= 1) {
        if (tid < off) sred[tid] += sred[tid + off];
        __syncthreads();
    }
    if (tid == 0)
        partials[(size_t)b * 512 + blockIdx.y * 16 + blockIdx.x] = sred[0];
}

__global__ __launch_bounds__(256) void k_mean(const float* __restrict__ partials,
                                              float* __restrict__ means)
{
    int b = blockIdx.x;
    int t = threadIdx.x;
    float s = partials[(size_t)b * 512 + t] + partials[(size_t)b * 512 + t + 256];
    __shared__ float sr[256];
    sr[t] = s;
    __syncthreads();
    for (int off = 128; off > 0; off >>= 1) {
        if (t < off) sr[t] += sr[t + off];
        __syncthreads();
    }
    if (t == 0) means[b] = sr[0] * (1.f / (float)PLANE);
}

__device__ __forceinline__ void jit1(float& r, float& g, float& bl,
                                     float mean, float cf, float sf, float hsh)
{
    r  = clip01(cf * r + (1.f - cf) * mean);
    g  = clip01(cf * g + (1.f - cf) * mean);
    bl = clip01(cf * bl + (1.f - cf) * mean);

    float gray = 0.299f * r + 0.587f * g + 0.114f * bl;
    r  = clip01(sf * r + (1.f - sf) * gray);
    g  = clip01(sf * g + (1.f - sf) * gray);
    bl = clip01(sf * bl + (1.f - sf) * gray);

    float maxc = fmaxf(fmaxf(r, g), bl);
    float minc = fminf(fminf(r, g), bl);
    float delta = maxc - minc;
    float sgm = delta / (maxc + 1e-8f);
    float dd = delta + 1e-8f;
    float rc = (maxc - r) / dd;
    float gc = (maxc - g) / dd;
    float bc = (maxc - bl) / dd;
    float h6 = (maxc == r) ? (bc - gc) : ((maxc == g) ? (2.f + rc - bc) : (4.f + gc - rc));
    float h = h6 * (1.f / 6.f);
    h = h - floorf(h);
    h = h + hsh;
    h = h - floorf(h);

    float hi = floorf(h * 6.f);
    float f = h * 6.f - hi;
    float v = maxc;
    float p = v * (1.f - sgm);
    float q = v * (1.f - f * sgm);
    float t = v * (1.f - (1.f - f) * sgm);
    int i = ((int)hi) % 6;
    if (i < 0) i += 6;
    float ro, go, bo;
    switch (i) {
        case 0: ro = v; go = t; bo = p; break;
        case 1: ro = q; go = v; bo = p; break;
        case 2: ro = p; go = v; bo = t; break;
        case 3: ro = p; go = q; bo = v; break;
        case 4: ro = t; go = p; bo = v; break;
        default: ro = v; go = p; bo = q; break;
    }
    r = clip01(ro); g = clip01(go); bl = clip01(bo);
}

__global__ __launch_bounds__(256) void k_jitter(const unsigned short* __restrict__ pre,
                                                const float* __restrict__ means,
                                                const float* __restrict__ contrast,
                                                const float* __restrict__ saturation,
                                                const float* __restrict__ hue,
                                                float* __restrict__ oimgs)
{
    int b = blockIdx.y;
    size_t i4 = (size_t)blockIdx.x * 256 + threadIdx.x;   // group of 4 px
    const unsigned short* pb = pre + (size_t)b * 3 * PLANE;

    uint2 ur = *(const uint2*)(pb + i4 * 4);
    uint2 ug = *(const uint2*)(pb + PLANE + i4 * 4);
    uint2 ub = *(const uint2*)(pb + 2 * PLANE + i4 * 4);

    float2 r01 = __half22float2(*(__half2*)&ur.x);
    float2 r23 = __half22float2(*(__half2*)&ur.y);
    float2 g01 = __half22float2(*(__half2*)&ug.x);
    float2 g23 = __half22float2(*(__half2*)&ug.y);
    float2 b01 = __half22float2(*(__half2*)&ub.x);
    float2 b23 = __half22float2(*(__half2*)&ub.y);

    float4 R  = make_float4(r01.x, r01.y, r23.x, r23.y);
    float4 G  = make_float4(g01.x, g01.y, g23.x, g23.y);
    float4 Bv = make_float4(b01.x, b01.y, b23.x, b23.y);

    float mean = means[b];
    float cf = contrast[b], sf = saturation[b], hsh = hue[b];

    jit1(R.x, G.x, Bv.x, mean, cf, sf, hsh);
    jit1(R.y, G.y, Bv.y, mean, cf, sf, hsh);
    jit1(R.z, G.z, Bv.z, mean, cf, sf, hsh);
    jit1(R.w, G.w, Bv.w, mean, cf, sf, hsh);

    size_t po = (size_t)b * 3 * PLANE + i4 * 4;
    *(float4*)(oimgs + po)             = R;
    *(float4*)(oimgs + po + PLANE)     = G;
    *(float4*)(oimgs + po + 2 * PLANE) = Bv;
}

extern "C" void kernel_launch(void* const* d_in, const int* in_sizes, int n_in,
                              void* d_out, int out_size, void* d_ws, size_t ws_size,
                              hipStream_t stream)
{
    const float* imgs       = (const float*)d_in[0];
    const float* masks      = (const float*)d_in[1];
    const int*   hflip      = (const int*)d_in[2];
    const int*   vflip      = (const int*)d_in[3];
    const float* angles     = (const float*)d_in[4];
    const float* translate  = (const float*)d_in[5];
    const float* scale      = (const float*)d_in[6];
    const float* brightness = (const float*)d_in[7];
    const float* contrast   = (const float*)d_in[8];
    const float* saturation = (const float*)d_in[9];
    const float* hue        = (const float*)d_in[10];

    float* oimgs  = (float*)d_out;
    float* omasks = oimgs + (size_t)Bd * 3 * PLANE;

    ushort4* rot         = (ushort4*)d_ws;                               // 8B * Bd*PLANE
    unsigned short* pre  = (unsigned short*)(rot + (size_t)Bd * PLANE);  // 2B * 3*Bd*PLANE
    float* partials      = (float*)(pre + (size_t)3 * Bd * PLANE);       // Bd*512
    float* means         = partials + (size_t)Bd * 512;                  // Bd

    dim3 blk1(16, 16);
    dim3 grd1(Wd / 16, Hd / 16, Bd);
    k_rotate<<<grd1, blk1, 0, stream>>>(imgs, masks, hflip, vflip, angles, rot);

    dim3 blk2(16, 16);
    dim3 grd2(Wd / 32, Hd / 16, Bd);
    k_affine<<<grd2, blk2, 0, stream>>>(rot, translate, scale, brightness,
                                        pre, omasks, partials);

    k_mean<<<Bd, 256, 0, stream>>>(partials, means);

    dim3 grd3(PLANE / 4 / 256, Bd);
    k_jitter<<<grd3, 256, 0, stream>>>(pre, means, contrast, saturation, hue, oimgs);
}